// Round 1
// baseline (929.666 us; speedup 1.0000x reference)
//
#include <hip/hip_runtime.h>
#include <math.h>

#define DIM_ 512
#define HID_ 2048
#define B_ 8
#define N_ 1024
#define ROWS_ 8192   // B_*N_
#define TOPK 24

__device__ __forceinline__ float sigm(float x) { return 1.f / (1.f + __expf(-x)); }

// ---------------- pooled = mean over N ----------------
__global__ __launch_bounds__(512)
void pool_part_kernel(const float* __restrict__ x, float* __restrict__ part) {
    // blockIdx.x in [0, 8*32): b = bx>>5, chunk = bx&31 covers 32 rows
    const int bx = blockIdx.x;
    const int b = bx >> 5, chunk = bx & 31;
    const int c = threadIdx.x;                     // 512
    const float* xb = x + ((long long)b * N_ + chunk * 32) * DIM_ + c;
    float s = 0.f;
    for (int n = 0; n < 32; ++n) s += xb[(long long)n * DIM_];
    part[(long long)bx * DIM_ + c] = s;
}

__global__ __launch_bounds__(512)
void pool_reduce_kernel(const float* __restrict__ part, float* __restrict__ pooled) {
    const int b = blockIdx.x;
    const int c = threadIdx.x;
    float s = 0.f;
    for (int g = 0; g < 32; ++g) s += part[((long long)b * 32 + g) * DIM_ + c];
    pooled[b * DIM_ + c] = s * (1.f / 1024.f);
}

// ---------------- head nets: k_cont (B,3), w (B,3) ----------------
__global__ __launch_bounds__(128)
void heads_kernel(const float* __restrict__ pooled,
                  const float* __restrict__ k1w, const float* __restrict__ k1b,
                  const float* __restrict__ k2w, const float* __restrict__ k2b,
                  const float* __restrict__ w1w, const float* __restrict__ w1b,
                  const float* __restrict__ w2w, const float* __restrict__ w2b,
                  float* __restrict__ kcont, float* __restrict__ wbr) {
    const int b = blockIdx.x;
    const int t = threadIdx.x;                     // 128
    __shared__ float sp[DIM_];
    __shared__ float kh[128], wh[128];
    __shared__ float wraw[4];
    for (int i = t; i < DIM_; i += 128) sp[i] = pooled[b * DIM_ + i];
    __syncthreads();
    float ak = k1b[t], aw = w1b[t];
    for (int k = 0; k < DIM_; ++k) {
        float pv = sp[k];
        ak = fmaf(pv, k1w[t * DIM_ + k], ak);
        aw = fmaf(pv, w1w[t * DIM_ + k], aw);
    }
    kh[t] = fmaxf(ak, 0.f);
    wh[t] = fmaxf(aw, 0.f);
    __syncthreads();
    if (t < 3) {
        float rk = k2b[t], rw = w2b[t];
        for (int k = 0; k < 128; ++k) {
            rk = fmaf(kh[k], k2w[t * 128 + k], rk);
            rw = fmaf(wh[k], w2w[t * 128 + k], rw);
        }
        kcont[b * 3 + t] = 1.f + 11.f * sigm(rk);   // K_MIN + ratio*(K_MAX-K_MIN)
        wraw[t] = rw;
    }
    __syncthreads();
    if (t == 0) {
        float m = fmaxf(wraw[0], fmaxf(wraw[1], wraw[2]));
        float e0 = __expf(wraw[0] - m), e1 = __expf(wraw[1] - m), e2 = __expf(wraw[2] - m);
        float inv = 1.f / (e0 + e1 + e2);
        wbr[b * 3 + 0] = e0 * inv;
        wbr[b * 3 + 1] = e1 * inv;
        wbr[b * 3 + 2] = e2 * inv;
    }
}

// ---------------- fp32 tiled NT GEMM: C[m,n] = act(sum_k A[m,k]*B[n,k] + bias[n]) ----------------
template<bool RELU, bool BIAS>
__global__ __launch_bounds__(256)
void gemm_nt(const float* __restrict__ A, const float* __restrict__ Bm,
             const float* __restrict__ bias, float* __restrict__ C,
             int M, int N, int K,
             long long sA, long long sB, long long sC) {
    const int bz = blockIdx.z;
    A  += (long long)bz * sA;
    Bm += (long long)bz * sB;
    C  += (long long)bz * sC;
    __shared__ float As[16][68];
    __shared__ float Bs[16][68];
    const int tid = threadIdx.x;
    const int tx = tid & 15, ty = tid >> 4;
    const int m0 = blockIdx.y * 64, n0 = blockIdx.x * 64;
    const int lr = tid >> 2;            // 0..63
    const int lc = (tid & 3) << 2;      // 0,4,8,12
    float acc[4][4] = {{0.f}};
    const float* Aptr = A + (long long)(m0 + lr) * K + lc;
    const float* Bptr = Bm + (long long)(n0 + lr) * K + lc;
    for (int k0 = 0; k0 < K; k0 += 16) {
        float4 a4 = *(const float4*)(Aptr + k0);
        float4 b4 = *(const float4*)(Bptr + k0);
        __syncthreads();
        As[lc + 0][lr] = a4.x; As[lc + 1][lr] = a4.y; As[lc + 2][lr] = a4.z; As[lc + 3][lr] = a4.w;
        Bs[lc + 0][lr] = b4.x; Bs[lc + 1][lr] = b4.y; Bs[lc + 2][lr] = b4.z; Bs[lc + 3][lr] = b4.w;
        __syncthreads();
#pragma unroll
        for (int k = 0; k < 16; ++k) {
            float4 av = *(const float4*)&As[k][ty << 2];
            float4 bv = *(const float4*)&Bs[k][tx << 2];
            float a[4] = {av.x, av.y, av.z, av.w};
            float b[4] = {bv.x, bv.y, bv.z, bv.w};
#pragma unroll
            for (int i = 0; i < 4; ++i)
#pragma unroll
                for (int j = 0; j < 4; ++j)
                    acc[i][j] = fmaf(a[i], b[j], acc[i][j]);
        }
    }
#pragma unroll
    for (int i = 0; i < 4; ++i) {
        const int m = m0 + (ty << 2) + i;
#pragma unroll
        for (int j = 0; j < 4; ++j) {
            const int n = n0 + (tx << 2) + j;
            float v = acc[i][j];
            if (BIAS) v += bias[n];
            if (RELU) v = fmaxf(v, 0.f);
            C[(long long)m * N + n] = v;
        }
    }
}

// ---------------- per-row: softmax stats + bitonic argsort + top-24 combined coefs ----------------
__global__ __launch_bounds__(256)
void topk_kernel(const float* __restrict__ sim,
                 const float* __restrict__ kcont, const float* __restrict__ wbr,
                 int* __restrict__ gidx, float* __restrict__ gcoef) {
    __shared__ float sv[1024];
    __shared__ int si[1024];
    __shared__ float red[256];
    const int row = blockIdx.x;        // 8192
    const int b = row >> 10;
    const int tid = threadIdx.x;       // 256
    const float* srow = sim + (long long)row * N_;
    for (int i = tid; i < 1024; i += 256) { sv[i] = srow[i]; si[i] = i; }
    __syncthreads();
    // row max
    float lm = -3.4e38f;
    for (int i = tid; i < 1024; i += 256) lm = fmaxf(lm, sv[i]);
    red[tid] = lm;
    __syncthreads();
    for (int s = 128; s > 0; s >>= 1) {
        if (tid < s) red[tid] = fmaxf(red[tid], red[tid + s]);
        __syncthreads();
    }
    const float maxv = red[0];
    __syncthreads();
    // softmax denominator over full row
    float ls = 0.f;
    for (int i = tid; i < 1024; i += 256) ls += __expf(sv[i] - maxv);
    red[tid] = ls;
    __syncthreads();
    for (int s = 128; s > 0; s >>= 1) {
        if (tid < s) red[tid] += red[tid + s];
        __syncthreads();
    }
    const float denom = red[0];
    // bitonic sort, descending by value, ascending index on ties (== stable argsort of -sim)
    for (int k = 2; k <= 1024; k <<= 1) {
        for (int j = k >> 1; j > 0; j >>= 1) {
            __syncthreads();
            for (int t = tid; t < 512; t += 256) {
                const int mask = j - 1;
                const int i = ((t & ~mask) << 1) | (t & mask);
                const int p = i | j;
                const float av = sv[i], bv = sv[p];
                const int ai = si[i], bi = si[p];
                // "av comes after bv" in descending stable order
                const bool after = (av < bv) || (av == bv && ai > bi);
                if (after == ((i & k) == 0)) {
                    sv[i] = bv; sv[p] = av;
                    si[i] = bi; si[p] = ai;
                }
            }
        }
    }
    __syncthreads();
    if (tid == 0) {
        const float invden = 1.f / denom;
        const float kc0 = kcont[b * 3 + 0], kc1 = kcont[b * 3 + 1], kc2 = kcont[b * 3 + 2];
        const float w0 = wbr[b * 3 + 0], w1 = wbr[b * 3 + 1], w2 = wbr[b * 3 + 2];
        float s0 = 0.f, s1 = 0.f, s2 = 0.f;
        for (int r = 0; r < TOPK; ++r) {
            const float p = __expf(sv[r] - maxv) * invden;
            const float rr = (float)r + 0.5f;
            s0 += p * sigm(12.f * (kc0 - rr));
            s1 += p * sigm(12.f * (kc1 - rr));
            s2 += p * sigm(12.f * (kc2 - rr));
        }
        const float f0 = w0 / (s0 + 1e-8f);
        const float f1 = w1 / (s1 + 1e-8f);
        const float f2 = w2 / (s2 + 1e-8f);
        for (int r = 0; r < TOPK; ++r) {
            const float p = __expf(sv[r] - maxv) * invden;
            const float rr = (float)r + 0.5f;
            const float coef = p * (f0 * sigm(12.f * (kc0 - rr)) +
                                    f1 * sigm(12.f * (kc1 - rr)) +
                                    f2 * sigm(12.f * (kc2 - rr)));
            gidx[row * TOPK + r] = si[r];
            gcoef[row * TOPK + r] = coef;
        }
    }
}

// ---------------- sparse aggregate: y[row,:] = sum_r coef_r * h[b, idx_r, :] ----------------
__global__ __launch_bounds__(128)
void aggregate_kernel(const float* __restrict__ h, const float* __restrict__ gcoef,
                      const int* __restrict__ gidx, float* __restrict__ y) {
    const int row = blockIdx.x;       // 8192
    const int b = row >> 10;
    const float* hb = h + (long long)b * (N_ * DIM_);
    __shared__ float sc[TOPK];
    __shared__ int sidx[TOPK];
    const int tid = threadIdx.x;      // 128
    if (tid < TOPK) { sc[tid] = gcoef[row * TOPK + tid]; sidx[tid] = gidx[row * TOPK + tid]; }
    __syncthreads();
    const int c = tid << 2;
    float4 acc = make_float4(0.f, 0.f, 0.f, 0.f);
#pragma unroll
    for (int r = 0; r < TOPK; ++r) {
        const float wv = sc[r];
        const float4 hv = *(const float4*)(hb + (long long)sidx[r] * DIM_ + c);
        acc.x = fmaf(wv, hv.x, acc.x);
        acc.y = fmaf(wv, hv.y, acc.y);
        acc.z = fmaf(wv, hv.z, acc.z);
        acc.w = fmaf(wv, hv.w, acc.w);
    }
    *(float4*)(y + (long long)row * DIM_ + c) = acc;
}

extern "C" void kernel_launch(void* const* d_in, const int* in_sizes, int n_in,
                              void* d_out, int out_size, void* d_ws, size_t ws_size,
                              hipStream_t stream) {
    const float* x     = (const float*)d_in[0];
    const float* fc1_w = (const float*)d_in[1];
    const float* fc1_b = (const float*)d_in[2];
    const float* fc2_w = (const float*)d_in[3];
    const float* fc2_b = (const float*)d_in[4];
    const float* k1_w  = (const float*)d_in[5];
    const float* k1_b  = (const float*)d_in[6];
    const float* k2_w  = (const float*)d_in[7];
    const float* k2_b  = (const float*)d_in[8];
    const float* w1_w  = (const float*)d_in[9];
    const float* w1_b  = (const float*)d_in[10];
    const float* w2_w  = (const float*)d_in[11];
    const float* w2_b  = (const float*)d_in[12];

    char* ws = (char*)d_ws;
    // workspace layout (bytes)
    float* h1     = (float*)(ws + 0);                      // 8192*2048*4 = 67,108,864
    float* simbuf = h1;                                    // reuse after h1 consumed (32 MB <= 64 MB)
    float* h      = (float*)(ws + 67108864);               // 8192*512*4 = 16,777,216
    float* ppart  = (float*)(ws + 83886080);               // 8*32*512*4 = 524,288
    float* pooled = (float*)(ws + 84410368);               // 16,384
    float* kcont  = (float*)(ws + 84426752);               // 96 (pad 128)
    float* wbr    = (float*)(ws + 84426880);               // 96 (pad 128)
    int*   topki  = (int*)  (ws + 84427008);               // 8192*24*4 = 786,432
    float* topkc  = (float*)(ws + 85213440);               // 786,432 -> end 85,999,872

    float* y = (float*)d_out;

    // 1) pooled mean
    pool_part_kernel<<<dim3(B_ * 32), dim3(512), 0, stream>>>(x, ppart);
    pool_reduce_kernel<<<dim3(B_), dim3(512), 0, stream>>>(ppart, pooled);
    // 2) head nets
    heads_kernel<<<dim3(B_), dim3(128), 0, stream>>>(pooled, k1_w, k1_b, k2_w, k2_b,
                                                     w1_w, w1_b, w2_w, w2_b, kcont, wbr);
    // 3) h1 = relu(x @ fc1_w^T + b1)   M=8192 N=2048 K=512
    gemm_nt<true, true><<<dim3(HID_ / 64, ROWS_ / 64, 1), dim3(256), 0, stream>>>(
        x, fc1_w, fc1_b, h1, ROWS_, HID_, DIM_, 0, 0, 0);
    // 4) h = h1 @ fc2_w^T + b2         M=8192 N=512 K=2048
    gemm_nt<false, true><<<dim3(DIM_ / 64, ROWS_ / 64, 1), dim3(256), 0, stream>>>(
        h1, fc2_w, fc2_b, h, ROWS_, DIM_, HID_, 0, 0, 0);
    // 5) sim[b] = h[b] @ h[b]^T        M=N=1024 K=512, batched z=8 (writes over h1 region)
    gemm_nt<false, false><<<dim3(N_ / 64, N_ / 64, B_), dim3(256), 0, stream>>>(
        h, h, nullptr, simbuf, N_, N_, DIM_,
        (long long)N_ * DIM_, (long long)N_ * DIM_, (long long)N_ * N_);
    // 6) per-row rank + combined top-24 coefficients
    topk_kernel<<<dim3(ROWS_), dim3(256), 0, stream>>>(simbuf, kcont, wbr, topki, topkc);
    // 7) sparse aggregate into output
    aggregate_kernel<<<dim3(ROWS_), dim3(128), 0, stream>>>(h, topkc, topki, y);
}

// Round 2
// 438.803 us; speedup vs baseline: 2.1186x; 2.1186x over previous
//
#include <hip/hip_runtime.h>
#include <math.h>

#define DIM_ 512
#define HID_ 2048
#define B_ 8
#define N_ 1024
#define ROWS_ 8192   // B_*N_
#define TOPK 24

typedef __attribute__((ext_vector_type(8))) short short8;
typedef __attribute__((ext_vector_type(4))) float float4v;

__device__ __forceinline__ float sigm(float x) { return 1.f / (1.f + __expf(-x)); }

__device__ __forceinline__ short f2bf(float f) {           // RNE fp32 -> bf16
    unsigned u = __float_as_uint(f);
    u += 0x7FFF + ((u >> 16) & 1);
    return (short)(u >> 16);
}

__device__ __forceinline__ void gload16(const short* g, short* l) {
    __builtin_amdgcn_global_load_lds(
        (const __attribute__((address_space(1))) void*)g,
        (__attribute__((address_space(3))) void*)l, 16, 0, 0);
}

// ---------------- fp32 -> bf16 conversion ----------------
__global__ __launch_bounds__(256)
void cvt_bf16_kernel(const float* __restrict__ in, short* __restrict__ out, int n4) {
    const int i = blockIdx.x * 256 + threadIdx.x;
    if (i < n4) {
        const float4 v = *(const float4*)(in + (long long)i * 4);
        short4 o;
        o.x = f2bf(v.x); o.y = f2bf(v.y); o.z = f2bf(v.z); o.w = f2bf(v.w);
        *(short4*)(out + (long long)i * 4) = o;
    }
}

// ---------------- pooled = mean over N ----------------
__global__ __launch_bounds__(512)
void pool_part_kernel(const float* __restrict__ x, float* __restrict__ part) {
    const int bx = blockIdx.x;
    const int b = bx >> 5, chunk = bx & 31;
    const int c = threadIdx.x;                     // 512
    const float* xb = x + ((long long)b * N_ + chunk * 32) * DIM_ + c;
    float s = 0.f;
    for (int n = 0; n < 32; ++n) s += xb[(long long)n * DIM_];
    part[(long long)bx * DIM_ + c] = s;
}

__global__ __launch_bounds__(512)
void pool_reduce_kernel(const float* __restrict__ part, float* __restrict__ pooled) {
    const int b = blockIdx.x;
    const int c = threadIdx.x;
    float s = 0.f;
    for (int g = 0; g < 32; ++g) s += part[((long long)b * 32 + g) * DIM_ + c];
    pooled[b * DIM_ + c] = s * (1.f / 1024.f);
}

// ---------------- head nets: k_cont (B,3), w (B,3) ----------------
__global__ __launch_bounds__(128)
void heads_kernel(const float* __restrict__ pooled,
                  const float* __restrict__ k1w, const float* __restrict__ k1b,
                  const float* __restrict__ k2w, const float* __restrict__ k2b,
                  const float* __restrict__ w1w, const float* __restrict__ w1b,
                  const float* __restrict__ w2w, const float* __restrict__ w2b,
                  float* __restrict__ kcont, float* __restrict__ wbr) {
    const int b = blockIdx.x;
    const int t = threadIdx.x;                     // 128
    __shared__ float sp[DIM_];
    __shared__ float kh[128], wh[128];
    __shared__ float wraw[4];
    for (int i = t; i < DIM_; i += 128) sp[i] = pooled[b * DIM_ + i];
    __syncthreads();
    float ak = k1b[t], aw = w1b[t];
    for (int k = 0; k < DIM_; ++k) {
        float pv = sp[k];
        ak = fmaf(pv, k1w[t * DIM_ + k], ak);
        aw = fmaf(pv, w1w[t * DIM_ + k], aw);
    }
    kh[t] = fmaxf(ak, 0.f);
    wh[t] = fmaxf(aw, 0.f);
    __syncthreads();
    if (t < 3) {
        float rk = k2b[t], rw = w2b[t];
        for (int k = 0; k < 128; ++k) {
            rk = fmaf(kh[k], k2w[t * 128 + k], rk);
            rw = fmaf(wh[k], w2w[t * 128 + k], rw);
        }
        kcont[b * 3 + t] = 1.f + 11.f * sigm(rk);
        wraw[t] = rw;
    }
    __syncthreads();
    if (t == 0) {
        float m = fmaxf(wraw[0], fmaxf(wraw[1], wraw[2]));
        float e0 = __expf(wraw[0] - m), e1 = __expf(wraw[1] - m), e2 = __expf(wraw[2] - m);
        float inv = 1.f / (e0 + e1 + e2);
        wbr[b * 3 + 0] = e0 * inv;
        wbr[b * 3 + 1] = e1 * inv;
        wbr[b * 3 + 2] = e2 * inv;
    }
}

// ---------------- bf16 MFMA NT GEMM: C[m,n] = act(sum_k A[m,k]*B[n,k] + bias[n]) ----------------
// 128x128 tile, BK=64, 4 waves (each 64x64 = 4x4 of 16x16x32 MFMA).
// LDS staged via global_load_lds width=16, XOR-swizzled chunks so ds_read_b128 is 2-way (free).
// OUTMODE: 0 = bf16 out, bias+relu (fc1); 1 = fp32 + bf16 out, bias (fc2); 2 = fp32 out, no bias (sim)
template<int OUTMODE>
__global__ __launch_bounds__(256)
void gemm_mfma(const short* __restrict__ A, const short* __restrict__ Bm,
               const float* __restrict__ bias,
               float* __restrict__ outF, short* __restrict__ outB,
               int M, int N, int K,
               long long sA, long long sB, long long sC) {
    const int bz = blockIdx.z;
    A  += (long long)bz * sA;
    Bm += (long long)bz * sB;

    __shared__ short As[128 * 64];
    __shared__ short Bs[128 * 64];

    const int tid = threadIdx.x;
    const int lane = tid & 63;
    const int wv = tid >> 6;                // 0..3
    const int m0 = blockIdx.y * 128;
    const int n0 = blockIdx.x * 128;

    const int lrow = lane >> 3;             // 0..7  (row within 8-row staging group)
    const int cg = (lane & 7) ^ lrow;       // global 8-elem chunk this lane fetches (XOR swizzle)

    const int ml = (wv & 1) * 64;           // wave's m-offset in tile
    const int nl = (wv >> 1) * 64;          // wave's n-offset in tile
    const int fr = lane & 15;               // fragment row index (m or n)
    const int kq = lane >> 4;               // k-quad 0..3

    float4v acc[4][4];
#pragma unroll
    for (int i = 0; i < 4; ++i)
#pragma unroll
        for (int j = 0; j < 4; ++j) acc[i][j] = (float4v){0.f, 0.f, 0.f, 0.f};

    for (int k0 = 0; k0 < K; k0 += 64) {
        __syncthreads();
#pragma unroll
        for (int i = 0; i < 4; ++i) {
            const int rloc = wv * 32 + i * 8 + lrow;
            gload16(A + (long long)(m0 + rloc) * K + (k0 + cg * 8),
                    &As[(wv * 32 + i * 8) * 64]);
            gload16(Bm + (long long)(n0 + rloc) * K + (k0 + cg * 8),
                    &Bs[(wv * 32 + i * 8) * 64]);
        }
        __syncthreads();
#pragma unroll
        for (int ks = 0; ks < 2; ++ks) {
            const int c = ks * 4 + kq;
            short8 af[4], bfr[4];
#pragma unroll
            for (int i = 0; i < 4; ++i) {
                const int m = ml + i * 16 + fr;
                af[i] = *(const short8*)&As[m * 64 + ((c ^ (m & 7)) * 8)];
                const int n = nl + i * 16 + fr;
                bfr[i] = *(const short8*)&Bs[n * 64 + ((c ^ (n & 7)) * 8)];
            }
#pragma unroll
            for (int i = 0; i < 4; ++i)
#pragma unroll
                for (int j = 0; j < 4; ++j)
                    acc[i][j] = __builtin_amdgcn_mfma_f32_16x16x32_bf16(
                        af[i], bfr[j], acc[i][j], 0, 0, 0);
        }
    }

    // epilogue: D row = kq*4 + reg (m-side), col = fr (n-side)
    const long long outOfs = (long long)bz * sC;
#pragma unroll
    for (int i = 0; i < 4; ++i) {
#pragma unroll
        for (int j = 0; j < 4; ++j) {
            const int ng = n0 + nl + j * 16 + fr;
            float bv = 0.f;
            if (OUTMODE != 2) bv = bias[ng];
#pragma unroll
            for (int r = 0; r < 4; ++r) {
                const int mg = m0 + ml + i * 16 + kq * 4 + r;
                float v = acc[i][j][r] + bv;
                if (OUTMODE == 0) v = fmaxf(v, 0.f);
                const long long idx = outOfs + (long long)mg * N + ng;
                if (OUTMODE != 0) outF[idx] = v;
                if (OUTMODE != 2) outB[idx] = f2bf(v);
            }
        }
    }
}

// ---------------- per-row: softmax stats + bitonic argsort + top-24 combined coefs ----------------
__global__ __launch_bounds__(256)
void topk_kernel(const float* __restrict__ sim,
                 const float* __restrict__ kcont, const float* __restrict__ wbr,
                 int* __restrict__ gidx, float* __restrict__ gcoef) {
    __shared__ float sv[1024];
    __shared__ int si[1024];
    __shared__ float red[256];
    const int row = blockIdx.x;        // 8192
    const int b = row >> 10;
    const int tid = threadIdx.x;       // 256
    const float* srow = sim + (long long)row * N_;
    for (int i = tid; i < 1024; i += 256) { sv[i] = srow[i]; si[i] = i; }
    __syncthreads();
    float lm = -3.4e38f;
    for (int i = tid; i < 1024; i += 256) lm = fmaxf(lm, sv[i]);
    red[tid] = lm;
    __syncthreads();
    for (int s = 128; s > 0; s >>= 1) {
        if (tid < s) red[tid] = fmaxf(red[tid], red[tid + s]);
        __syncthreads();
    }
    const float maxv = red[0];
    __syncthreads();
    float ls = 0.f;
    for (int i = tid; i < 1024; i += 256) ls += __expf(sv[i] - maxv);
    red[tid] = ls;
    __syncthreads();
    for (int s = 128; s > 0; s >>= 1) {
        if (tid < s) red[tid] += red[tid + s];
        __syncthreads();
    }
    const float denom = red[0];
    // bitonic sort, descending by value, ascending index on ties
    for (int k = 2; k <= 1024; k <<= 1) {
        for (int j = k >> 1; j > 0; j >>= 1) {
            __syncthreads();
            for (int t = tid; t < 512; t += 256) {
                const int mask = j - 1;
                const int i = ((t & ~mask) << 1) | (t & mask);
                const int p = i | j;
                const float av = sv[i], bv = sv[p];
                const int ai = si[i], bi = si[p];
                const bool after = (av < bv) || (av == bv && ai > bi);
                if (after == ((i & k) == 0)) {
                    sv[i] = bv; sv[p] = av;
                    si[i] = bi; si[p] = ai;
                }
            }
        }
    }
    __syncthreads();
    if (tid == 0) {
        const float invden = 1.f / denom;
        const float kc0 = kcont[b * 3 + 0], kc1 = kcont[b * 3 + 1], kc2 = kcont[b * 3 + 2];
        const float w0 = wbr[b * 3 + 0], w1 = wbr[b * 3 + 1], w2 = wbr[b * 3 + 2];
        float s0 = 0.f, s1 = 0.f, s2 = 0.f;
        for (int r = 0; r < TOPK; ++r) {
            const float p = __expf(sv[r] - maxv) * invden;
            const float rr = (float)r + 0.5f;
            s0 += p * sigm(12.f * (kc0 - rr));
            s1 += p * sigm(12.f * (kc1 - rr));
            s2 += p * sigm(12.f * (kc2 - rr));
        }
        const float f0 = w0 / (s0 + 1e-8f);
        const float f1 = w1 / (s1 + 1e-8f);
        const float f2 = w2 / (s2 + 1e-8f);
        for (int r = 0; r < TOPK; ++r) {
            const float p = __expf(sv[r] - maxv) * invden;
            const float rr = (float)r + 0.5f;
            const float coef = p * (f0 * sigm(12.f * (kc0 - rr)) +
                                    f1 * sigm(12.f * (kc1 - rr)) +
                                    f2 * sigm(12.f * (kc2 - rr)));
            gidx[row * TOPK + r] = si[r];
            gcoef[row * TOPK + r] = coef;
        }
    }
}

// ---------------- sparse aggregate: y[row,:] = sum_r coef_r * h[b, idx_r, :] ----------------
__global__ __launch_bounds__(128)
void aggregate_kernel(const float* __restrict__ h, const float* __restrict__ gcoef,
                      const int* __restrict__ gidx, float* __restrict__ y) {
    const int row = blockIdx.x;       // 8192
    const int b = row >> 10;
    const float* hb = h + (long long)b * (N_ * DIM_);
    __shared__ float sc[TOPK];
    __shared__ int sidx[TOPK];
    const int tid = threadIdx.x;      // 128
    if (tid < TOPK) { sc[tid] = gcoef[row * TOPK + tid]; sidx[tid] = gidx[row * TOPK + tid]; }
    __syncthreads();
    const int c = tid << 2;
    float4 acc = make_float4(0.f, 0.f, 0.f, 0.f);
#pragma unroll
    for (int r = 0; r < TOPK; ++r) {
        const float wv = sc[r];
        const float4 hv = *(const float4*)(hb + (long long)sidx[r] * DIM_ + c);
        acc.x = fmaf(wv, hv.x, acc.x);
        acc.y = fmaf(wv, hv.y, acc.y);
        acc.z = fmaf(wv, hv.z, acc.z);
        acc.w = fmaf(wv, hv.w, acc.w);
    }
    *(float4*)(y + (long long)row * DIM_ + c) = acc;
}

extern "C" void kernel_launch(void* const* d_in, const int* in_sizes, int n_in,
                              void* d_out, int out_size, void* d_ws, size_t ws_size,
                              hipStream_t stream) {
    const float* x     = (const float*)d_in[0];
    const float* fc1_w = (const float*)d_in[1];
    const float* fc1_b = (const float*)d_in[2];
    const float* fc2_w = (const float*)d_in[3];
    const float* fc2_b = (const float*)d_in[4];
    const float* k1_w  = (const float*)d_in[5];
    const float* k1_b  = (const float*)d_in[6];
    const float* k2_w  = (const float*)d_in[7];
    const float* k2_b  = (const float*)d_in[8];
    const float* w1_w  = (const float*)d_in[9];
    const float* w1_b  = (const float*)d_in[10];
    const float* w2_w  = (const float*)d_in[11];
    const float* w2_b  = (const float*)d_in[12];

    char* ws = (char*)d_ws;
    // workspace layout (bytes), all 256-aligned
    short* h1b    = (short*)(ws + 0);              // 8192*2048*2 = 33,554,432
    float* simbuf = (float*)(ws + 0);              // 8*1024*1024*4 = 33,554,432 (reuse after fc2)
    float* h      = (float*)(ws + 33554432);       // 8192*512*4 = 16,777,216
    short* hb     = (short*)(ws + 50331648);       // 8192*512*2 = 8,388,608
    short* xb     = (short*)(ws + 58720256);       // 8192*512*2 = 8,388,608
    short* w1b    = (short*)(ws + 67108864);       // 2048*512*2 = 2,097,152
    short* w2b    = (short*)(ws + 69206016);       // 512*2048*2 = 2,097,152
    float* ppart  = (float*)(ws + 71303168);       // 524,288
    float* pooled = (float*)(ws + 71827456);       // 16,384
    float* kcont  = (float*)(ws + 71843840);       // 128
    float* wbr    = (float*)(ws + 71843968);       // 128
    int*   topki  = (int*)  (ws + 71844096);       // 786,432
    float* topkc  = (float*)(ws + 72630528);       // 786,432 -> end 73,416,960

    float* y = (float*)d_out;

    // 0) bf16 conversions
    cvt_bf16_kernel<<<dim3((ROWS_ * DIM_ / 4 + 255) / 256), dim3(256), 0, stream>>>(x, xb, ROWS_ * DIM_ / 4);
    cvt_bf16_kernel<<<dim3((HID_ * DIM_ / 4 + 255) / 256), dim3(256), 0, stream>>>(fc1_w, w1b, HID_ * DIM_ / 4);
    cvt_bf16_kernel<<<dim3((DIM_ * HID_ / 4 + 255) / 256), dim3(256), 0, stream>>>(fc2_w, w2b, DIM_ * HID_ / 4);

    // 1) pooled mean + head nets (fp32, reads original x)
    pool_part_kernel<<<dim3(B_ * 32), dim3(512), 0, stream>>>(x, ppart);
    pool_reduce_kernel<<<dim3(B_), dim3(512), 0, stream>>>(ppart, pooled);
    heads_kernel<<<dim3(B_), dim3(128), 0, stream>>>(pooled, k1_w, k1_b, k2_w, k2_b,
                                                     w1_w, w1_b, w2_w, w2_b, kcont, wbr);

    // 2) h1 = relu(x @ fc1_w^T + b1) -> bf16   M=8192 N=2048 K=512
    gemm_mfma<0><<<dim3(HID_ / 128, ROWS_ / 128, 1), dim3(256), 0, stream>>>(
        xb, w1b, fc1_b, nullptr, h1b, ROWS_, HID_, DIM_, 0, 0, 0);
    // 3) h = h1 @ fc2_w^T + b2 -> fp32 + bf16  M=8192 N=512 K=2048
    gemm_mfma<1><<<dim3(DIM_ / 128, ROWS_ / 128, 1), dim3(256), 0, stream>>>(
        h1b, w2b, fc2_b, h, hb, ROWS_, DIM_, HID_, 0, 0, 0);
    // 4) sim[b] = h[b] @ h[b]^T -> fp32        M=N=1024 K=512, batch 8 (overwrites h1b)
    gemm_mfma<2><<<dim3(N_ / 128, N_ / 128, B_), dim3(256), 0, stream>>>(
        hb, hb, nullptr, simbuf, nullptr, N_, N_, DIM_,
        (long long)N_ * DIM_, (long long)N_ * DIM_, (long long)N_ * N_);

    // 5) per-row rank + combined top-24 coefficients
    topk_kernel<<<dim3(ROWS_), dim3(256), 0, stream>>>(simbuf, kcont, wbr, topki, topkc);
    // 6) sparse aggregate into output
    aggregate_kernel<<<dim3(ROWS_), dim3(128), 0, stream>>>(h, topkc, topki, y);
}

// Round 3
// 297.758 us; speedup vs baseline: 3.1222x; 1.4737x over previous
//
#include <hip/hip_runtime.h>
#include <math.h>

#define DIM_ 512
#define HID_ 2048
#define B_ 8
#define N_ 1024
#define ROWS_ 8192   // B_*N_
#define TOPK 24

typedef __attribute__((ext_vector_type(8))) short short8;
typedef __attribute__((ext_vector_type(4))) float float4v;

__device__ __forceinline__ float sigm(float x) { return 1.f / (1.f + __expf(-x)); }

__device__ __forceinline__ short f2bf(float f) {           // RNE fp32 -> bf16
    unsigned u = __float_as_uint(f);
    u += 0x7FFF + ((u >> 16) & 1);
    return (short)(u >> 16);
}

__device__ __forceinline__ unsigned f2ord(float f) {       // monotone fp32 -> u32
    unsigned u = __float_as_uint(f);
    return (u & 0x80000000u) ? ~u : (u | 0x80000000u);
}
__device__ __forceinline__ float ord2f(unsigned o) {
    unsigned u = (o & 0x80000000u) ? (o & 0x7FFFFFFFu) : ~o;
    return __uint_as_float(u);
}

__device__ __forceinline__ void gload16(const short* g, short* l) {
    __builtin_amdgcn_global_load_lds(
        (const __attribute__((address_space(1))) void*)g,
        (__attribute__((address_space(3))) void*)l, 16, 0, 0);
}

// ---------------- fp32 -> bf16 conversion ----------------
__global__ __launch_bounds__(256)
void cvt_bf16_kernel(const float* __restrict__ in, short* __restrict__ out, int n4) {
    const int i = blockIdx.x * 256 + threadIdx.x;
    if (i < n4) {
        const float4 v = *(const float4*)(in + (long long)i * 4);
        short4 o;
        o.x = f2bf(v.x); o.y = f2bf(v.y); o.z = f2bf(v.z); o.w = f2bf(v.w);
        *(short4*)(out + (long long)i * 4) = o;
    }
}

// ---------------- pooled = mean over N ----------------
__global__ __launch_bounds__(512)
void pool_part_kernel(const float* __restrict__ x, float* __restrict__ part) {
    const int bx = blockIdx.x;
    const int b = bx >> 5, chunk = bx & 31;
    const int c = threadIdx.x;                     // 512
    const float* xb = x + ((long long)b * N_ + chunk * 32) * DIM_ + c;
    float s = 0.f;
    for (int n = 0; n < 32; ++n) s += xb[(long long)n * DIM_];
    part[(long long)bx * DIM_ + c] = s;
}

__global__ __launch_bounds__(512)
void pool_reduce_kernel(const float* __restrict__ part, float* __restrict__ pooled) {
    const int b = blockIdx.x;
    const int c = threadIdx.x;
    float s = 0.f;
    for (int g = 0; g < 32; ++g) s += part[((long long)b * 32 + g) * DIM_ + c];
    pooled[b * DIM_ + c] = s * (1.f / 1024.f);
}

// ---------------- head nets: k_cont (B,3), w (B,3) ----------------
__global__ __launch_bounds__(128)
void heads_kernel(const float* __restrict__ pooled,
                  const float* __restrict__ k1w, const float* __restrict__ k1b,
                  const float* __restrict__ k2w, const float* __restrict__ k2b,
                  const float* __restrict__ w1w, const float* __restrict__ w1b,
                  const float* __restrict__ w2w, const float* __restrict__ w2b,
                  float* __restrict__ kcont, float* __restrict__ wbr) {
    const int b = blockIdx.x;
    const int t = threadIdx.x;                     // 128
    __shared__ float sp[DIM_];
    __shared__ float kh[128], wh[128];
    __shared__ float wraw[4];
    for (int i = t; i < DIM_; i += 128) sp[i] = pooled[b * DIM_ + i];
    __syncthreads();
    float ak = k1b[t], aw = w1b[t];
    for (int k = 0; k < DIM_; ++k) {
        float pv = sp[k];
        ak = fmaf(pv, k1w[t * DIM_ + k], ak);
        aw = fmaf(pv, w1w[t * DIM_ + k], aw);
    }
    kh[t] = fmaxf(ak, 0.f);
    wh[t] = fmaxf(aw, 0.f);
    __syncthreads();
    if (t < 3) {
        float rk = k2b[t], rw = w2b[t];
        for (int k = 0; k < 128; ++k) {
            rk = fmaf(kh[k], k2w[t * 128 + k], rk);
            rw = fmaf(wh[k], w2w[t * 128 + k], rw);
        }
        kcont[b * 3 + t] = 1.f + 11.f * sigm(rk);
        wraw[t] = rw;
    }
    __syncthreads();
    if (t == 0) {
        float m = fmaxf(wraw[0], fmaxf(wraw[1], wraw[2]));
        float e0 = __expf(wraw[0] - m), e1 = __expf(wraw[1] - m), e2 = __expf(wraw[2] - m);
        float inv = 1.f / (e0 + e1 + e2);
        wbr[b * 3 + 0] = e0 * inv;
        wbr[b * 3 + 1] = e1 * inv;
        wbr[b * 3 + 2] = e2 * inv;
    }
}

// ---------------- bf16 MFMA NT GEMM (unchanged from R2) ----------------
template<int OUTMODE>
__global__ __launch_bounds__(256)
void gemm_mfma(const short* __restrict__ A, const short* __restrict__ Bm,
               const float* __restrict__ bias,
               float* __restrict__ outF, short* __restrict__ outB,
               int M, int N, int K,
               long long sA, long long sB, long long sC) {
    const int bz = blockIdx.z;
    A  += (long long)bz * sA;
    Bm += (long long)bz * sB;

    __shared__ short As[128 * 64];
    __shared__ short Bs[128 * 64];

    const int tid = threadIdx.x;
    const int lane = tid & 63;
    const int wv = tid >> 6;                // 0..3
    const int m0 = blockIdx.y * 128;
    const int n0 = blockIdx.x * 128;

    const int lrow = lane >> 3;             // 0..7
    const int cg = (lane & 7) ^ lrow;       // XOR swizzle

    const int ml = (wv & 1) * 64;
    const int nl = (wv >> 1) * 64;
    const int fr = lane & 15;
    const int kq = lane >> 4;

    float4v acc[4][4];
#pragma unroll
    for (int i = 0; i < 4; ++i)
#pragma unroll
        for (int j = 0; j < 4; ++j) acc[i][j] = (float4v){0.f, 0.f, 0.f, 0.f};

    for (int k0 = 0; k0 < K; k0 += 64) {
        __syncthreads();
#pragma unroll
        for (int i = 0; i < 4; ++i) {
            const int rloc = wv * 32 + i * 8 + lrow;
            gload16(A + (long long)(m0 + rloc) * K + (k0 + cg * 8),
                    &As[(wv * 32 + i * 8) * 64]);
            gload16(Bm + (long long)(n0 + rloc) * K + (k0 + cg * 8),
                    &Bs[(wv * 32 + i * 8) * 64]);
        }
        __syncthreads();
#pragma unroll
        for (int ks = 0; ks < 2; ++ks) {
            const int c = ks * 4 + kq;
            short8 af[4], bfr[4];
#pragma unroll
            for (int i = 0; i < 4; ++i) {
                const int m = ml + i * 16 + fr;
                af[i] = *(const short8*)&As[m * 64 + ((c ^ (m & 7)) * 8)];
                const int n = nl + i * 16 + fr;
                bfr[i] = *(const short8*)&Bs[n * 64 + ((c ^ (n & 7)) * 8)];
            }
#pragma unroll
            for (int i = 0; i < 4; ++i)
#pragma unroll
                for (int j = 0; j < 4; ++j)
                    acc[i][j] = __builtin_amdgcn_mfma_f32_16x16x32_bf16(
                        af[i], bfr[j], acc[i][j], 0, 0, 0);
        }
    }

    const long long outOfs = (long long)bz * sC;
#pragma unroll
    for (int i = 0; i < 4; ++i) {
#pragma unroll
        for (int j = 0; j < 4; ++j) {
            const int ng = n0 + nl + j * 16 + fr;
            float bv = 0.f;
            if (OUTMODE != 2) bv = bias[ng];
#pragma unroll
            for (int r = 0; r < 4; ++r) {
                const int mg = m0 + ml + i * 16 + kq * 4 + r;
                float v = acc[i][j][r] + bv;
                if (OUTMODE == 0) v = fmaxf(v, 0.f);
                const long long idx = outOfs + (long long)mg * N + ng;
                if (OUTMODE != 0) outF[idx] = v;
                if (OUTMODE != 2) outB[idx] = f2bf(v);
            }
        }
    }
}

// ---------------- per-row wave top-24: shuffle-only selection ----------------
// One wave per row; each lane holds 16 values in registers. u64 keys give
// exact descending-value / ascending-index order (matches stable argsort).
__global__ __launch_bounds__(256)
void topk_kernel(const float* __restrict__ sim,
                 const float* __restrict__ kcont, const float* __restrict__ wbr,
                 int* __restrict__ gidx, float* __restrict__ gcoef) {
    const int wv = threadIdx.x >> 6;
    const int lane = threadIdx.x & 63;
    const int row = blockIdx.x * 4 + wv;          // 2048 blocks * 4 waves
    const int b = row >> 10;
    const float* srow = sim + (long long)row * N_;

    float f[16];
    const int base = lane * 16;
#pragma unroll
    for (int q = 0; q < 4; ++q) {
        const float4 v = *(const float4*)(srow + base + q * 4);
        f[q * 4 + 0] = v.x; f[q * 4 + 1] = v.y; f[q * 4 + 2] = v.z; f[q * 4 + 3] = v.w;
    }

    // row max (float butterfly)
    float lmax = f[0];
#pragma unroll
    for (int j = 1; j < 16; ++j) lmax = fmaxf(lmax, f[j]);
#pragma unroll
    for (int d = 32; d > 0; d >>= 1) lmax = fmaxf(lmax, __shfl_xor(lmax, d));
    const float maxv = lmax;

    // softmax denominator
    float lsum = 0.f;
#pragma unroll
    for (int j = 0; j < 16; ++j) lsum += __expf(f[j] - maxv);
#pragma unroll
    for (int d = 32; d > 0; d >>= 1) lsum += __shfl_xor(lsum, d);
    const float invden = 1.f / lsum;

    // keys: (orderable(value) << 32) | (1024 - idx); low word unique in [1,1024]
    unsigned long long s[16];
#pragma unroll
    for (int j = 0; j < 16; ++j)
        s[j] = ((unsigned long long)f2ord(f[j]) << 32) | (unsigned)(1024 - (base + j));

    const float kc0 = kcont[b * 3 + 0], kc1 = kcont[b * 3 + 1], kc2 = kcont[b * 3 + 2];
    const float w0 = wbr[b * 3 + 0], w1 = wbr[b * 3 + 1], w2 = wbr[b * 3 + 2];

    float s0 = 0.f, s1 = 0.f, s2 = 0.f;
    float myp = 0.f;
    int myidx = 0;
    unsigned prevlo = 0xFFFFFFFFu;                 // nothing matches on iter 0

#pragma unroll
    for (int r = 0; r < TOPK; ++r) {
        // fused: remove previous winner (unique low-32 match) + lane-local max
        unsigned long long lm = 0;
#pragma unroll
        for (int j = 0; j < 16; ++j) {
            if ((unsigned)s[j] == prevlo) s[j] = 0;
            lm = (s[j] > lm) ? s[j] : lm;
        }
        // butterfly max across 64 lanes
        unsigned long long gm = lm;
#pragma unroll
        for (int d = 32; d > 0; d >>= 1) {
            unsigned long long o = __shfl_xor(gm, d);
            gm = (o > gm) ? o : gm;
        }
        prevlo = (unsigned)gm;
        const float v = ord2f((unsigned)(gm >> 32));
        const int idx = 1024 - (int)(gm & 0xFFFFFFFFu);
        const float p = __expf(v - maxv) * invden;
        const float rr = (float)r + 0.5f;
        s0 += p * sigm(12.f * (kc0 - rr));
        s1 += p * sigm(12.f * (kc1 - rr));
        s2 += p * sigm(12.f * (kc2 - rr));
        if (lane == r) { myp = p; myidx = idx; }
    }

    const float f0 = w0 / (s0 + 1e-8f);
    const float f1 = w1 / (s1 + 1e-8f);
    const float f2 = w2 / (s2 + 1e-8f);
    if (lane < TOPK) {
        const float rr = (float)lane + 0.5f;
        const float coef = myp * (f0 * sigm(12.f * (kc0 - rr)) +
                                  f1 * sigm(12.f * (kc1 - rr)) +
                                  f2 * sigm(12.f * (kc2 - rr)));
        gidx[row * TOPK + lane] = myidx;
        gcoef[row * TOPK + lane] = coef;
    }
}

// ---------------- sparse aggregate: y[row,:] = sum_r coef_r * h[b, idx_r, :] ----------------
__global__ __launch_bounds__(128)
void aggregate_kernel(const float* __restrict__ h, const float* __restrict__ gcoef,
                      const int* __restrict__ gidx, float* __restrict__ y) {
    const int row = blockIdx.x;       // 8192
    const int b = row >> 10;
    const float* hb = h + (long long)b * (N_ * DIM_);
    __shared__ float sc[TOPK];
    __shared__ int sidx[TOPK];
    const int tid = threadIdx.x;      // 128
    if (tid < TOPK) { sc[tid] = gcoef[row * TOPK + tid]; sidx[tid] = gidx[row * TOPK + tid]; }
    __syncthreads();
    const int c = tid << 2;
    float4 acc = make_float4(0.f, 0.f, 0.f, 0.f);
#pragma unroll
    for (int r = 0; r < TOPK; ++r) {
        const float wv = sc[r];
        const float4 hv = *(const float4*)(hb + (long long)sidx[r] * DIM_ + c);
        acc.x = fmaf(wv, hv.x, acc.x);
        acc.y = fmaf(wv, hv.y, acc.y);
        acc.z = fmaf(wv, hv.z, acc.z);
        acc.w = fmaf(wv, hv.w, acc.w);
    }
    *(float4*)(y + (long long)row * DIM_ + c) = acc;
}

extern "C" void kernel_launch(void* const* d_in, const int* in_sizes, int n_in,
                              void* d_out, int out_size, void* d_ws, size_t ws_size,
                              hipStream_t stream) {
    const float* x     = (const float*)d_in[0];
    const float* fc1_w = (const float*)d_in[1];
    const float* fc1_b = (const float*)d_in[2];
    const float* fc2_w = (const float*)d_in[3];
    const float* fc2_b = (const float*)d_in[4];
    const float* k1_w  = (const float*)d_in[5];
    const float* k1_b  = (const float*)d_in[6];
    const float* k2_w  = (const float*)d_in[7];
    const float* k2_b  = (const float*)d_in[8];
    const float* w1_w  = (const float*)d_in[9];
    const float* w1_b  = (const float*)d_in[10];
    const float* w2_w  = (const float*)d_in[11];
    const float* w2_b  = (const float*)d_in[12];

    char* ws = (char*)d_ws;
    short* h1b    = (short*)(ws + 0);              // 33,554,432
    float* simbuf = (float*)(ws + 0);              // 33,554,432 (reuse after fc2)
    float* h      = (float*)(ws + 33554432);       // 16,777,216
    short* hb     = (short*)(ws + 50331648);       // 8,388,608
    short* xb     = (short*)(ws + 58720256);       // 8,388,608
    short* w1b    = (short*)(ws + 67108864);       // 2,097,152
    short* w2b    = (short*)(ws + 69206016);       // 2,097,152
    float* ppart  = (float*)(ws + 71303168);       // 524,288
    float* pooled = (float*)(ws + 71827456);       // 16,384
    float* kcont  = (float*)(ws + 71843840);       // 128
    float* wbr    = (float*)(ws + 71843968);       // 128
    int*   topki  = (int*)  (ws + 71844096);       // 786,432
    float* topkc  = (float*)(ws + 72630528);       // 786,432

    float* y = (float*)d_out;

    cvt_bf16_kernel<<<dim3((ROWS_ * DIM_ / 4 + 255) / 256), dim3(256), 0, stream>>>(x, xb, ROWS_ * DIM_ / 4);
    cvt_bf16_kernel<<<dim3((HID_ * DIM_ / 4 + 255) / 256), dim3(256), 0, stream>>>(fc1_w, w1b, HID_ * DIM_ / 4);
    cvt_bf16_kernel<<<dim3((DIM_ * HID_ / 4 + 255) / 256), dim3(256), 0, stream>>>(fc2_w, w2b, DIM_ * HID_ / 4);

    pool_part_kernel<<<dim3(B_ * 32), dim3(512), 0, stream>>>(x, ppart);
    pool_reduce_kernel<<<dim3(B_), dim3(512), 0, stream>>>(ppart, pooled);
    heads_kernel<<<dim3(B_), dim3(128), 0, stream>>>(pooled, k1_w, k1_b, k2_w, k2_b,
                                                     w1_w, w1_b, w2_w, w2_b, kcont, wbr);

    gemm_mfma<0><<<dim3(HID_ / 128, ROWS_ / 128, 1), dim3(256), 0, stream>>>(
        xb, w1b, fc1_b, nullptr, h1b, ROWS_, HID_, DIM_, 0, 0, 0);
    gemm_mfma<1><<<dim3(DIM_ / 128, ROWS_ / 128, 1), dim3(256), 0, stream>>>(
        h1b, w2b, fc2_b, h, hb, ROWS_, DIM_, HID_, 0, 0, 0);
    gemm_mfma<2><<<dim3(N_ / 128, N_ / 128, B_), dim3(256), 0, stream>>>(
        hb, hb, nullptr, simbuf, nullptr, N_, N_, DIM_,
        (long long)N_ * DIM_, (long long)N_ * DIM_, (long long)N_ * N_);

    topk_kernel<<<dim3(ROWS_ / 4), dim3(256), 0, stream>>>(simbuf, kcont, wbr, topki, topkc);
    aggregate_kernel<<<dim3(ROWS_), dim3(128), 0, stream>>>(h, topkc, topki, y);
}

// Round 5
// 259.528 us; speedup vs baseline: 3.5821x; 1.1473x over previous
//
#include <hip/hip_runtime.h>
#include <math.h>

#define DIM_ 512
#define HID_ 2048
#define B_ 8
#define N_ 1024
#define ROWS_ 8192   // B_*N_
#define TOPK 16      // exact: gate at rank>=16 is <= e^-54 (k<12), contribution ~1e-20

typedef __attribute__((ext_vector_type(8))) short short8;
typedef __attribute__((ext_vector_type(4))) float float4v;

__device__ __forceinline__ float sigm(float x) { return 1.f / (1.f + __expf(-x)); }

__device__ __forceinline__ short f2bf(float f) {           // RNE fp32 -> bf16
    unsigned u = __float_as_uint(f);
    u += 0x7FFF + ((u >> 16) & 1);
    return (short)(u >> 16);
}

__device__ __forceinline__ float bf2f(unsigned short s) {
    return __uint_as_float((unsigned)s << 16);
}

__device__ __forceinline__ unsigned f2ord(float f) {       // monotone fp32 -> u32
    unsigned u = __float_as_uint(f);
    return (u & 0x80000000u) ? ~u : (u | 0x80000000u);
}
__device__ __forceinline__ float ord2f(unsigned o) {
    unsigned u = (o & 0x80000000u) ? (o & 0x7FFFFFFFu) : ~o;
    return __uint_as_float(u);
}

__device__ __forceinline__ void gload16(const short* g, short* l) {
    __builtin_amdgcn_global_load_lds(
        (const __attribute__((address_space(1))) void*)g,
        (__attribute__((address_space(3))) void*)l, 16, 0, 0);
}

// ---------------- fp32 -> bf16 conversion ----------------
__global__ __launch_bounds__(256)
void cvt_bf16_kernel(const float* __restrict__ in, short* __restrict__ out, int n4) {
    const int i = blockIdx.x * 256 + threadIdx.x;
    if (i < n4) {
        const float4 v = *(const float4*)(in + (long long)i * 4);
        short4 o;
        o.x = f2bf(v.x); o.y = f2bf(v.y); o.z = f2bf(v.z); o.w = f2bf(v.w);
        *(short4*)(out + (long long)i * 4) = o;
    }
}

// ---------------- pooled = mean over N ----------------
__global__ __launch_bounds__(512)
void pool_part_kernel(const float* __restrict__ x, float* __restrict__ part) {
    const int bx = blockIdx.x;
    const int b = bx >> 5, chunk = bx & 31;
    const int c = threadIdx.x;                     // 512
    const float* xb = x + ((long long)b * N_ + chunk * 32) * DIM_ + c;
    float s = 0.f;
    for (int n = 0; n < 32; ++n) s += xb[(long long)n * DIM_];
    part[(long long)bx * DIM_ + c] = s;
}

__global__ __launch_bounds__(512)
void pool_reduce_kernel(const float* __restrict__ part, float* __restrict__ pooled) {
    const int b = blockIdx.x;
    const int c = threadIdx.x;
    float s = 0.f;
    for (int g = 0; g < 32; ++g) s += part[((long long)b * 32 + g) * DIM_ + c];
    pooled[b * DIM_ + c] = s * (1.f / 1024.f);
}

// ---------------- head nets: k_cont (B,3), w (B,3) ----------------
__global__ __launch_bounds__(128)
void heads_kernel(const float* __restrict__ pooled,
                  const float* __restrict__ k1w, const float* __restrict__ k1b,
                  const float* __restrict__ k2w, const float* __restrict__ k2b,
                  const float* __restrict__ w1w, const float* __restrict__ w1b,
                  const float* __restrict__ w2w, const float* __restrict__ w2b,
                  float* __restrict__ kcont, float* __restrict__ wbr) {
    const int b = blockIdx.x;
    const int t = threadIdx.x;                     // 128
    __shared__ float sp[DIM_];
    __shared__ float kh[128], wh[128];
    __shared__ float wraw[4];
    for (int i = t; i < DIM_; i += 128) sp[i] = pooled[b * DIM_ + i];
    __syncthreads();
    float ak = k1b[t], aw = w1b[t];
    for (int k = 0; k < DIM_; ++k) {
        float pv = sp[k];
        ak = fmaf(pv, k1w[t * DIM_ + k], ak);
        aw = fmaf(pv, w1w[t * DIM_ + k], aw);
    }
    kh[t] = fmaxf(ak, 0.f);
    wh[t] = fmaxf(aw, 0.f);
    __syncthreads();
    if (t < 3) {
        float rk = k2b[t], rw = w2b[t];
        for (int k = 0; k < 128; ++k) {
            rk = fmaf(kh[k], k2w[t * 128 + k], rk);
            rw = fmaf(wh[k], w2w[t * 128 + k], rw);
        }
        kcont[b * 3 + t] = 1.f + 11.f * sigm(rk);
        wraw[t] = rw;
    }
    __syncthreads();
    if (t == 0) {
        float m = fmaxf(wraw[0], fmaxf(wraw[1], wraw[2]));
        float e0 = __expf(wraw[0] - m), e1 = __expf(wraw[1] - m), e2 = __expf(wraw[2] - m);
        float inv = 1.f / (e0 + e1 + e2);
        wbr[b * 3 + 0] = e0 * inv;
        wbr[b * 3 + 1] = e1 * inv;
        wbr[b * 3 + 2] = e2 * inv;
    }
}

// ---------------- bf16 MFMA NT GEMM ----------------
// 128x128 tile, BK=64, 4 waves (each 64x64 = 4x4 of 16x16x32 MFMA).
// lda/ldb = row strides (allow split-K views). sA/sB/sC = per-z element offsets.
// OUTMODE: 0 = bf16 out, bias+relu; 1 = bf16 out, bias; 2 = fp32 raw out (no bias)
template<int OUTMODE>
__global__ __launch_bounds__(256)
void gemm_mfma(const short* __restrict__ A, const short* __restrict__ Bm,
               const float* __restrict__ bias,
               float* __restrict__ outF, short* __restrict__ outB,
               int M, int N, int K, int lda, int ldb,
               long long sA, long long sB, long long sC) {
    const int bz = blockIdx.z;
    A  += (long long)bz * sA;
    Bm += (long long)bz * sB;

    __shared__ short As[128 * 64];
    __shared__ short Bs[128 * 64];

    const int tid = threadIdx.x;
    const int lane = tid & 63;
    const int wv = tid >> 6;                // 0..3
    const int m0 = blockIdx.y * 128;
    const int n0 = blockIdx.x * 128;

    const int lrow = lane >> 3;             // 0..7
    const int cg = (lane & 7) ^ lrow;       // XOR swizzle

    const int ml = (wv & 1) * 64;
    const int nl = (wv >> 1) * 64;
    const int fr = lane & 15;
    const int kq = lane >> 4;

    float4v acc[4][4];
#pragma unroll
    for (int i = 0; i < 4; ++i)
#pragma unroll
        for (int j = 0; j < 4; ++j) acc[i][j] = (float4v){0.f, 0.f, 0.f, 0.f};

    for (int k0 = 0; k0 < K; k0 += 64) {
        __syncthreads();
#pragma unroll
        for (int i = 0; i < 4; ++i) {
            const int rloc = wv * 32 + i * 8 + lrow;
            gload16(A + (long long)(m0 + rloc) * lda + (k0 + cg * 8),
                    &As[(wv * 32 + i * 8) * 64]);
            gload16(Bm + (long long)(n0 + rloc) * ldb + (k0 + cg * 8),
                    &Bs[(wv * 32 + i * 8) * 64]);
        }
        __syncthreads();
#pragma unroll
        for (int ks = 0; ks < 2; ++ks) {
            const int c = ks * 4 + kq;
            short8 af[4], bfr[4];
#pragma unroll
            for (int i = 0; i < 4; ++i) {
                const int m = ml + i * 16 + fr;
                af[i] = *(const short8*)&As[m * 64 + ((c ^ (m & 7)) * 8)];
                const int n = nl + i * 16 + fr;
                bfr[i] = *(const short8*)&Bs[n * 64 + ((c ^ (n & 7)) * 8)];
            }
#pragma unroll
            for (int i = 0; i < 4; ++i)
#pragma unroll
                for (int j = 0; j < 4; ++j)
                    acc[i][j] = __builtin_amdgcn_mfma_f32_16x16x32_bf16(
                        af[i], bfr[j], acc[i][j], 0, 0, 0);
        }
    }

    const long long outOfs = (long long)bz * sC;
#pragma unroll
    for (int i = 0; i < 4; ++i) {
#pragma unroll
        for (int j = 0; j < 4; ++j) {
            const int ng = n0 + nl + j * 16 + fr;
            float bv = 0.f;
            if (OUTMODE != 2) bv = bias[ng];
#pragma unroll
            for (int r = 0; r < 4; ++r) {
                const int mg = m0 + ml + i * 16 + kq * 4 + r;
                float v = acc[i][j][r] + bv;
                if (OUTMODE == 0) v = fmaxf(v, 0.f);
                const long long idx = outOfs + (long long)mg * N + ng;
                if (OUTMODE == 2) outF[idx] = v;
                else              outB[idx] = f2bf(v);
            }
        }
    }
}

// ---------------- split-K combine: hb = bf16(p0 + p1 + bias) ----------------
__global__ __launch_bounds__(256)
void combine_kernel(const float* __restrict__ p0, const float* __restrict__ p1,
                    const float* __restrict__ bias, short* __restrict__ out) {
    const int i = blockIdx.x * 256 + threadIdx.x;     // over 4M/4 elements
    const long long o = (long long)i * 4;
    const float4 a = *(const float4*)(p0 + o);
    const float4 b = *(const float4*)(p1 + o);
    const int col = (int)(o & (DIM_ - 1));
    const float4 bs = *(const float4*)(bias + col);
    short4 r;
    r.x = f2bf(a.x + b.x + bs.x);
    r.y = f2bf(a.y + b.y + bs.y);
    r.z = f2bf(a.z + b.z + bs.z);
    r.w = f2bf(a.w + b.w + bs.w);
    *(short4*)(out + o) = r;
}

// ---------------- per-row wave top-16: shuffle-only selection ----------------
__global__ __launch_bounds__(256)
void topk_kernel(const float* __restrict__ sim,
                 const float* __restrict__ kcont, const float* __restrict__ wbr,
                 int* __restrict__ gidx, float* __restrict__ gcoef) {
    const int wv = threadIdx.x >> 6;
    const int lane = threadIdx.x & 63;
    const int row = blockIdx.x * 4 + wv;          // 2048 blocks * 4 waves
    const int b = row >> 10;
    const float* srow = sim + (long long)row * N_;

    float f[16];
    const int base = lane * 16;
#pragma unroll
    for (int q = 0; q < 4; ++q) {
        const float4 v = *(const float4*)(srow + base + q * 4);
        f[q * 4 + 0] = v.x; f[q * 4 + 1] = v.y; f[q * 4 + 2] = v.z; f[q * 4 + 3] = v.w;
    }

    // row max
    float lmax = f[0];
#pragma unroll
    for (int j = 1; j < 16; ++j) lmax = fmaxf(lmax, f[j]);
#pragma unroll
    for (int d = 32; d > 0; d >>= 1) lmax = fmaxf(lmax, __shfl_xor(lmax, d));
    const float maxv = lmax;

    // softmax denominator (full row)
    float lsum = 0.f;
#pragma unroll
    for (int j = 0; j < 16; ++j) lsum += __expf(f[j] - maxv);
#pragma unroll
    for (int d = 32; d > 0; d >>= 1) lsum += __shfl_xor(lsum, d);
    const float invden = 1.f / lsum;

    // keys: (orderable(value) << 32) | (1024 - idx); low word unique in [1,1024]
    unsigned long long s[16];
#pragma unroll
    for (int j = 0; j < 16; ++j)
        s[j] = ((unsigned long long)f2ord(f[j]) << 32) | (unsigned)(1024 - (base + j));

    const float kc0 = kcont[b * 3 + 0], kc1 = kcont[b * 3 + 1], kc2 = kcont[b * 3 + 2];
    const float w0 = wbr[b * 3 + 0], w1 = wbr[b * 3 + 1], w2 = wbr[b * 3 + 2];

    float s0 = 0.f, s1 = 0.f, s2 = 0.f;
    float myp = 0.f;
    int myidx = 0;
    unsigned prevlo = 0xFFFFFFFFu;

#pragma unroll
    for (int r = 0; r < TOPK; ++r) {
        unsigned long long lm = 0;
#pragma unroll
        for (int j = 0; j < 16; ++j) {
            if ((unsigned)s[j] == prevlo) s[j] = 0;
            lm = (s[j] > lm) ? s[j] : lm;
        }
        unsigned long long gm = lm;
#pragma unroll
        for (int d = 32; d > 0; d >>= 1) {
            unsigned long long o = __shfl_xor(gm, d);
            gm = (o > gm) ? o : gm;
        }
        prevlo = (unsigned)gm;
        const float v = ord2f((unsigned)(gm >> 32));
        const int idx = 1024 - (int)(gm & 0xFFFFFFFFu);
        const float p = __expf(v - maxv) * invden;
        const float rr = (float)r + 0.5f;
        s0 += p * sigm(12.f * (kc0 - rr));
        s1 += p * sigm(12.f * (kc1 - rr));
        s2 += p * sigm(12.f * (kc2 - rr));
        if (lane == r) { myp = p; myidx = idx; }
    }

    const float f0 = w0 / (s0 + 1e-8f);
    const float f1 = w1 / (s1 + 1e-8f);
    const float f2 = w2 / (s2 + 1e-8f);
    if (lane < TOPK) {
        const float rr = (float)lane + 0.5f;
        const float coef = myp * (f0 * sigm(12.f * (kc0 - rr)) +
                                  f1 * sigm(12.f * (kc1 - rr)) +
                                  f2 * sigm(12.f * (kc2 - rr)));
        gidx[row * TOPK + lane] = myidx;
        gcoef[row * TOPK + lane] = coef;
    }
}

// ---------------- sparse aggregate (bf16 h): y[row,:] = sum_r coef_r * h[b, idx_r, :] ----------------
__global__ __launch_bounds__(128)
void aggregate_kernel(const unsigned short* __restrict__ h, const float* __restrict__ gcoef,
                      const int* __restrict__ gidx, float* __restrict__ y) {
    const int row = blockIdx.x;       // 8192
    const int b = row >> 10;
    const unsigned short* hb = h + (long long)b * (N_ * DIM_);
    __shared__ float sc[TOPK];
    __shared__ int sidx[TOPK];
    const int tid = threadIdx.x;      // 128
    if (tid < TOPK) { sc[tid] = gcoef[row * TOPK + tid]; sidx[tid] = gidx[row * TOPK + tid]; }
    __syncthreads();
    const int c = tid << 2;
    float4 acc = make_float4(0.f, 0.f, 0.f, 0.f);
#pragma unroll
    for (int r = 0; r < TOPK; ++r) {
        const float wv = sc[r];
        const ushort4 hv = *(const ushort4*)(hb + (long long)sidx[r] * DIM_ + c);
        acc.x = fmaf(wv, bf2f(hv.x), acc.x);
        acc.y = fmaf(wv, bf2f(hv.y), acc.y);
        acc.z = fmaf(wv, bf2f(hv.z), acc.z);
        acc.w = fmaf(wv, bf2f(hv.w), acc.w);
    }
    *(float4*)(y + (long long)row * DIM_ + c) = acc;
}

extern "C" void kernel_launch(void* const* d_in, const int* in_sizes, int n_in,
                              void* d_out, int out_size, void* d_ws, size_t ws_size,
                              hipStream_t stream) {
    const float* x     = (const float*)d_in[0];
    const float* fc1_w = (const float*)d_in[1];
    const float* fc1_b = (const float*)d_in[2];
    const float* fc2_w = (const float*)d_in[3];
    const float* fc2_b = (const float*)d_in[4];
    const float* k1_w  = (const float*)d_in[5];
    const float* k1_b  = (const float*)d_in[6];
    const float* k2_w  = (const float*)d_in[7];
    const float* k2_b  = (const float*)d_in[8];
    const float* w1_w  = (const float*)d_in[9];
    const float* w1_b  = (const float*)d_in[10];
    const float* w2_w  = (const float*)d_in[11];
    const float* w2_b  = (const float*)d_in[12];

    char* ws = (char*)d_ws;
    // timeline-overlapped layout (single stream => sequential):
    //   [0, 33.5M):   h1b (bf16, live fc1->fc2)  then simbuf (fp32, live sim->topk)
    //   [33.5M, 67.1M): xb (bf16, live cvt->fc1) then partial0/1 (fp32, live fc2->combine)
    short* h1b    = (short*)(ws + 0);              // 33,554,432
    float* simbuf = (float*)(ws + 0);
    short* xb     = (short*)(ws + 33554432);       // 8,388,608 (dead before partials written)
    float* part0  = (float*)(ws + 33554432);       // 16,777,216
    float* part1  = (float*)(ws + 50331648);       // 16,777,216
    short* hb     = (short*)(ws + 67108864);       // 8,388,608
    short* w1b    = (short*)(ws + 75497472);       // 2,097,152
    short* w2b    = (short*)(ws + 77594624);       // 2,097,152
    float* ppart  = (float*)(ws + 79691776);       // 524,288
    float* pooled = (float*)(ws + 80216064);       // 16,384
    float* kcont  = (float*)(ws + 80232448);       // 128
    float* wbr    = (float*)(ws + 80232576);       // 128
    int*   topki  = (int*)  (ws + 80232704);       // 8192*16*4 = 524,288
    float* topkc  = (float*)(ws + 80756992);       // 524,288 -> end 81,281,280

    float* y = (float*)d_out;

    // 0) bf16 conversions
    cvt_bf16_kernel<<<dim3(ROWS_ * DIM_ / 4 / 256), dim3(256), 0, stream>>>(x, xb, ROWS_ * DIM_ / 4);
    cvt_bf16_kernel<<<dim3(HID_ * DIM_ / 4 / 256), dim3(256), 0, stream>>>(fc1_w, w1b, HID_ * DIM_ / 4);
    cvt_bf16_kernel<<<dim3(DIM_ * HID_ / 4 / 256), dim3(256), 0, stream>>>(fc2_w, w2b, DIM_ * HID_ / 4);

    // 1) pooled mean + head nets
    pool_part_kernel<<<dim3(B_ * 32), dim3(512), 0, stream>>>(x, ppart);
    pool_reduce_kernel<<<dim3(B_), dim3(512), 0, stream>>>(ppart, pooled);
    heads_kernel<<<dim3(B_), dim3(128), 0, stream>>>(pooled, k1_w, k1_b, k2_w, k2_b,
                                                     w1_w, w1_b, w2_w, w2_b, kcont, wbr);

    // 2) h1 = relu(x @ fc1_w^T + b1) -> bf16    M=8192 N=2048 K=512
    gemm_mfma<0><<<dim3(HID_ / 128, ROWS_ / 128, 1), dim3(256), 0, stream>>>(
        xb, w1b, fc1_b, nullptr, h1b, ROWS_, HID_, DIM_, DIM_, DIM_, 0, 0, 0);
    // 3) fc2 split-K=2: partial[z] = h1[:, z*1024:+1024] @ w2[:, z*1024:+1024]^T (fp32 raw)
    gemm_mfma<2><<<dim3(DIM_ / 128, ROWS_ / 128, 2), dim3(256), 0, stream>>>(
        h1b, w2b, nullptr, part0, nullptr, ROWS_, DIM_, HID_ / 2, HID_, HID_,
        (long long)(HID_ / 2), (long long)(HID_ / 2), (long long)ROWS_ * DIM_);
    //    combine: hb = bf16(p0 + p1 + bias)
    combine_kernel<<<dim3(ROWS_ * DIM_ / 4 / 256), dim3(256), 0, stream>>>(part0, part1, fc2_b, hb);
    // 4) sim[b] = hb[b] @ hb[b]^T -> fp32       M=N=1024 K=512, batch 8 (overwrites h1b)
    gemm_mfma<2><<<dim3(N_ / 128, N_ / 128, B_), dim3(256), 0, stream>>>(
        hb, hb, nullptr, simbuf, nullptr, N_, N_, DIM_, DIM_, DIM_,
        (long long)N_ * DIM_, (long long)N_ * DIM_, (long long)N_ * N_);

    // 5) per-row top-16 rank extraction + combined coefficients
    topk_kernel<<<dim3(ROWS_ / 4), dim3(256), 0, stream>>>(simbuf, kcont, wbr, topki, topkc);
    // 6) sparse aggregate into output
    aggregate_kernel<<<dim3(ROWS_), dim3(128), 0, stream>>>(
        (const unsigned short*)hb, topkc, topki, y);
}